// Round 4
// baseline (74.892 us; speedup 1.0000x reference)
//
#include <hip/hip_runtime.h>
#include <math.h>

#define TT 8192
#define DD 4096

typedef float  f32x4  __attribute__((ext_vector_type(4)));
typedef short  bf16x8 __attribute__((ext_vector_type(8)));
typedef unsigned int u32;

// ---------------- Kernel P: split weights into 3 bf16 planes, frag-ordered ----------------
// wfrag word layout: ((p*128 + s)*2 + h)*256 + l*4  (uint4 per lane = 8 bf16)
// k = s*32 + (l>>4)*8 + i ; expert e = h*16 + (l&15).
__global__ __launch_bounds__(128)
void split_w(const float* __restrict__ gw1, const float* __restrict__ nw,
             u32* __restrict__ wfrag) {
  const int s = blockIdx.x;          // 128 k-steps
  const int t = threadIdx.x;
  const int h = t >> 6, l = t & 63;
  const int e = h * 16 + (l & 15);
  const float* src = ((e < 16) ? (gw1 + (size_t)e * DD) : (nw + (size_t)(e - 16) * DD))
                     + s * 32 + ((l >> 4) << 3);
  float f[8];
  *(float4*)&f[0] = *(const float4*)src;
  *(float4*)&f[4] = *(const float4*)(src + 4);
  u32 u0[8], u1[8], u2[8];
#pragma unroll
  for (int i = 0; i < 8; ++i) {
    u0[i] = __float_as_uint(f[i]);
    const float r1 = f[i] - __uint_as_float(u0[i] & 0xFFFF0000u);
    u1[i] = __float_as_uint(r1);
    const float r2 = r1 - __uint_as_float(u1[i] & 0xFFFF0000u);
    u2[i] = __float_as_uint(r2);
  }
  const size_t base = ((size_t)s * 2 + h) * 256 + l * 4;
#define PK(U) make_uint4((U[0]>>16)|(U[1]&0xFFFF0000u), (U[2]>>16)|(U[3]&0xFFFF0000u), \
                         (U[4]>>16)|(U[5]&0xFFFF0000u), (U[6]>>16)|(U[7]&0xFFFF0000u))
  *(uint4*)(wfrag + base)                 = PK(u0);
  *(uint4*)(wfrag + base + 128 * 512)     = PK(u1);   // plane stride = 128*2*256 words
  *(uint4*)(wfrag + base + 2 * 128 * 512) = PK(u2);
#undef PK
}

// ---------------- Kernel M: fused GEMM + in-block k-reduction + epilogue ----------------
// 512 blocks x 8 waves; block owns 16 rows, wave w owns k-slice w*512.
// x loaded NON-TEMPORAL (zero reuse; keeps wfrag L2-resident).
// Prefetch rings (x depth-3, B depth-2) pinned by sched_barrier(0) per k-step so the
// scheduler cannot sink the loads back to their uses: ~10 loads stay in flight.
// Numerics identical to prior rounds (same split ops, same MFMA order, same reduce tree).
__global__ __launch_bounds__(512, 4)
void gate_mega(const float* __restrict__ x, const u32* __restrict__ wfrag,
               const float* __restrict__ noise, const float* __restrict__ gw2,
               float* __restrict__ out, float* __restrict__ part2) {
  __shared__ float red[8][512];      // [wave][e*16 + row]
  __shared__ float sg2[256];
  const int t = threadIdx.x;
  const int w = t >> 6, l = t & 63;
  const int rt = blockIdx.x;         // 16-row tile 0..511
  if (t < 256) sg2[t] = gw2[t];

  const int r = l & 15, c = l >> 4;
  const float* xp = x + (size_t)(rt * 16 + r) * DD + w * 512 + (c << 3);
  const u32* wfl = wfrag + (size_t)l * 4 + (size_t)(w * 16) * 512;

  f32x4 ag0 = {0,0,0,0}, ag1 = ag0, ag2 = ag0, an0 = ag0, an1 = ag0, an2 = ag0;

  f32x4  fx[3][2];    // x prefetch ring, depth 3 (nt loads, ext-vector type)
  bf16x8 bw[2][6];    // wfrag prefetch ring, depth 2

#define LDX(slot, sl_) do { \
    fx[slot][0] = __builtin_nontemporal_load((const f32x4*)(xp + (sl_) * 32)); \
    fx[slot][1] = __builtin_nontemporal_load((const f32x4*)(xp + (sl_) * 32 + 4)); \
  } while (0)
#define LDB(slot, sl_) do { \
    const u32* wb_ = wfl + (size_t)(sl_) * 512; \
    bw[slot][0] = *(const bf16x8*)(wb_); \
    bw[slot][1] = *(const bf16x8*)(wb_ + 256); \
    bw[slot][2] = *(const bf16x8*)(wb_ + 128 * 512); \
    bw[slot][3] = *(const bf16x8*)(wb_ + 128 * 512 + 256); \
    bw[slot][4] = *(const bf16x8*)(wb_ + 2 * 128 * 512); \
    bw[slot][5] = *(const bf16x8*)(wb_ + 2 * 128 * 512 + 256); \
  } while (0)

  LDX(0, 0);
  LDX(1, 1);
  LDB(0, 0);

#pragma unroll
  for (int sl = 0; sl < 16; ++sl) {
    const int xs = sl % 3;           // constant under full unroll
    const int ws = sl & 1;

    // prefetch: x for sl+2, B for sl+1 (issued BEFORE compute, pinned below)
    if (sl + 2 < 16) LDX((sl + 2) % 3, sl + 2);
    if (sl + 1 < 16) LDB((sl + 1) & 1, sl + 1);
    __builtin_amdgcn_sched_barrier(0);   // loads may not sink below this point

    // split current x slice (consumes fx[xs], loaded 2 iterations ago)
    u32 pk[12] __attribute__((aligned(16)));
#pragma unroll
    for (int p = 0; p < 4; ++p) {
      const float fa = fx[xs][p >> 1][(p & 1) * 2];
      const float fb = fx[xs][p >> 1][(p & 1) * 2 + 1];
      const u32  a  = __float_as_uint(fa);
      const float ra1 = fa - __uint_as_float(a & 0xFFFF0000u);
      const u32  a1 = __float_as_uint(ra1);
      const float ra2 = ra1 - __uint_as_float(a1 & 0xFFFF0000u);
      const u32  a2 = __float_as_uint(ra2);
      const u32  b  = __float_as_uint(fb);
      const float rb1 = fb - __uint_as_float(b & 0xFFFF0000u);
      const u32  b1 = __float_as_uint(rb1);
      const float rb2 = rb1 - __uint_as_float(b1 & 0xFFFF0000u);
      const u32  b2 = __float_as_uint(rb2);
      pk[p]     = (a  >> 16) | (b  & 0xFFFF0000u);
      pk[4 + p] = (a1 >> 16) | (b1 & 0xFFFF0000u);
      pk[8 + p] = (a2 >> 16) | (b2 & 0xFFFF0000u);
    }
    const bf16x8 a0 = *(const bf16x8*)&pk[0];
    const bf16x8 a1 = *(const bf16x8*)&pk[4];
    const bf16x8 a2 = *(const bf16x8*)&pk[8];

    ag0 = __builtin_amdgcn_mfma_f32_16x16x32_bf16(a0, bw[ws][0], ag0, 0, 0, 0);
    an0 = __builtin_amdgcn_mfma_f32_16x16x32_bf16(a0, bw[ws][1], an0, 0, 0, 0);
    ag1 = __builtin_amdgcn_mfma_f32_16x16x32_bf16(a0, bw[ws][2], ag1, 0, 0, 0);
    an1 = __builtin_amdgcn_mfma_f32_16x16x32_bf16(a0, bw[ws][3], an1, 0, 0, 0);
    ag2 = __builtin_amdgcn_mfma_f32_16x16x32_bf16(a1, bw[ws][0], ag2, 0, 0, 0);
    an2 = __builtin_amdgcn_mfma_f32_16x16x32_bf16(a1, bw[ws][1], an2, 0, 0, 0);
    ag0 = __builtin_amdgcn_mfma_f32_16x16x32_bf16(a0, bw[ws][4], ag0, 0, 0, 0);
    an0 = __builtin_amdgcn_mfma_f32_16x16x32_bf16(a0, bw[ws][5], an0, 0, 0, 0);
    ag1 = __builtin_amdgcn_mfma_f32_16x16x32_bf16(a1, bw[ws][2], ag1, 0, 0, 0);
    an1 = __builtin_amdgcn_mfma_f32_16x16x32_bf16(a1, bw[ws][3], an1, 0, 0, 0);
    ag2 = __builtin_amdgcn_mfma_f32_16x16x32_bf16(a2, bw[ws][0], ag2, 0, 0, 0);
    an2 = __builtin_amdgcn_mfma_f32_16x16x32_bf16(a2, bw[ws][1], an2, 0, 0, 0);
  }
#undef LDX
#undef LDB

  const f32x4 cg = ag0 + ag1 + ag2;
  const f32x4 cn = an0 + an1 + an2;
  // C/D: col(lane&15)=expert, row=(lane>>4)*4+reg [m89]. Store as [e*16+row].
#pragma unroll
  for (int j = 0; j < 4; ++j) {
    red[w][r * 16 + (c * 4 + j)]        = cg[j];
    red[w][(16 + r) * 16 + (c * 4 + j)] = cn[j];
  }
  __syncthreads();
  // 512-thread reduce across the 8 k-slices, ascending order (bitwise-stable).
  {
    float s = red[0][t];
#pragma unroll
    for (int ww = 1; ww < 8; ++ww) s += red[ww][t];
    red[0][t] = s;   // column-exclusive per thread: no race
  }
  __syncthreads();

  if (t < 16) {
    const int row = rt * 16 + t;
    float dot[32];
#pragma unroll
    for (int e = 0; e < 32; ++e) dot[e] = red[0][e * 16 + t];
    float h[16];
#pragma unroll
    for (int e = 0; e < 16; ++e) h[e] = tanhf(dot[e]);
    float lg[16], nc[16], ln[16], lo[16];
#pragma unroll
    for (int j = 0; j < 16; ++j) {
      float s = 0.f;
#pragma unroll
      for (int e = 0; e < 16; ++e) s = fmaf(h[e], sg2[j * 16 + e], s);
      lg[j] = s;
      const float v = dot[16 + j];
      nc[j] = fmaxf(v, 0.f) + log1pf(expf(-fabsf(v))) + 0.01f;
      ln[j] = noise[(size_t)row * 16 + j] * nc[j];
      lo[j] = lg[j] + ln[j];
    }
    int i0 = 0; float m0 = lo[0];
#pragma unroll
    for (int j = 1; j < 16; ++j) if (lo[j] > m0) { m0 = lo[j]; i0 = j; }
    int i1 = -1; float m1 = -1e30f;
#pragma unroll
    for (int j = 0; j < 16; ++j) if (j != i0 && lo[j] > m1) { m1 = lo[j]; i1 = j; }
    float m2 = -1e30f;
#pragma unroll
    for (int j = 0; j < 16; ++j) if (j != i0 && j != i1 && lo[j] > m2) m2 = lo[j];

    const float e1 = expf(m1 - m0);
    const float s0 = 1.f / (1.f + e1);
    const float s1 = e1 / (1.f + e1);
    out[(size_t)row * 2]             = (float)i0;
    out[(size_t)row * 2 + 1]         = (float)i1;
    out[16384 + (size_t)row * 2]     = s0;
    out[16384 + (size_t)row * 2 + 1] = s1;

    float cacc[32];
#pragma unroll
    for (int j = 0; j < 16; ++j) {
      cacc[j] = (j == i0) ? s0 : ((j == i1) ? s1 : 0.f);
      const bool in = ln[j] > m2;
      const float thr = in ? m2 : m1;
      const float z = (lg[j] - thr) / nc[j];
      cacc[16 + j] = 0.5f * (1.f + erff(z * 0.70710678118654752f));
    }
    // reduce the 32 loss partials across the 16 row-lanes
#pragma unroll
    for (int off = 1; off < 16; off <<= 1) {
#pragma unroll
      for (int k = 0; k < 32; ++k) cacc[k] += __shfl_xor(cacc[k], off, 16);
    }
    // lane t writes partial for expert t (static selection to avoid scratch)
    float v0 = 0.f, v1 = 0.f;
#pragma unroll
    for (int k = 0; k < 16; ++k) if (t == k) { v0 = cacc[k]; v1 = cacc[16 + k]; }
    part2[(size_t)rt * 32 + t]      = v0;
    part2[(size_t)rt * 32 + 16 + t] = v1;
  }
}

// ---------------- Kernel C: reduce per-block partials -> cv^2 loss ----------------
__global__ __launch_bounds__(256)
void gate_loss_k(const float* __restrict__ part2, float* __restrict__ out) {
  __shared__ float sred[8][32];
  const int t = threadIdx.x;        // 256
  const int k = t & 31, s = t >> 5; // expert, block-slice (8 slices of 64 blocks)
  float acc = 0.f;
#pragma unroll 8
  for (int i = 0; i < 64; ++i) acc += part2[(size_t)(s * 64 + i) * 32 + k];
  sred[s][k] = acc;
  __syncthreads();
  if (t == 0) {
    float res = 0.f;
    for (int g = 0; g < 2; ++g) {
      float vals[16];
      float mu = 0.f;
      for (int j = 0; j < 16; ++j) {
        float s2 = 0.f;
        for (int ss = 0; ss < 8; ++ss) s2 += sred[ss][g * 16 + j];
        vals[j] = s2;
        mu += s2;
      }
      mu *= (1.f / 16.f);
      float var = 0.f;
      for (int j = 0; j < 16; ++j) { const float d = vals[j] - mu; var += d * d; }
      var *= (1.f / 15.f);
      res += var / (mu * mu + 1e-10f);
    }
    out[32768] = res * 0.01f;
  }
}

extern "C" void kernel_launch(void* const* d_in, const int* in_sizes, int n_in,
                              void* d_out, int out_size, void* d_ws, size_t ws_size,
                              hipStream_t stream) {
  const float* x     = (const float*)d_in[0];
  const float* gw1   = (const float*)d_in[1];
  const float* gw2   = (const float*)d_in[2];
  const float* nw    = (const float*)d_in[3];
  const float* noise = (const float*)d_in[4];
  float* out   = (float*)d_out;
  u32*   wfrag = (u32*)d_ws;                                   // 768 KB, fully written
  float* part2 = (float*)((char*)d_ws + (size_t)768 * 1024);   // 64 KB, fully written
  split_w<<<128, 128, 0, stream>>>(gw1, nw, wfrag);
  gate_mega<<<512, 512, 0, stream>>>(x, wfrag, noise, gw2, out, part2);
  gate_loss_k<<<1, 256, 0, stream>>>(part2, out);
}

// Round 5
// 63.067 us; speedup vs baseline: 1.1875x; 1.1875x over previous
//
#include <hip/hip_runtime.h>
#include <math.h>

#define TT 8192
#define DD 4096

typedef float  f32x4  __attribute__((ext_vector_type(4)));
typedef short  bf16x8 __attribute__((ext_vector_type(8)));
typedef unsigned int u32;

typedef __attribute__((address_space(3))) void        lds_vp;
typedef const __attribute__((address_space(1))) void  gbl_vp;
// async global->LDS: lane l's 16B lands at lptr + l*16 (wave-uniform lptr)
#define GLD(gp_, lp_) __builtin_amdgcn_global_load_lds((gbl_vp*)(gp_), (lds_vp*)(lp_), 16, 0, 0)

// ---------------- Kernel P: split weights into 3 bf16 planes, frag-ordered ----------------
// wfrag word layout: ((p*128 + s)*2 + h)*256 + l*4  (uint4 per lane = 8 bf16)
// k = s*32 + (l>>4)*8 + i ; expert e = h*16 + (l&15).
__global__ __launch_bounds__(128)
void split_w(const float* __restrict__ gw1, const float* __restrict__ nw,
             u32* __restrict__ wfrag) {
  const int s = blockIdx.x;          // 128 k-steps
  const int t = threadIdx.x;
  const int h = t >> 6, l = t & 63;
  const int e = h * 16 + (l & 15);
  const float* src = ((e < 16) ? (gw1 + (size_t)e * DD) : (nw + (size_t)(e - 16) * DD))
                     + s * 32 + ((l >> 4) << 3);
  float f[8];
  *(float4*)&f[0] = *(const float4*)src;
  *(float4*)&f[4] = *(const float4*)(src + 4);
  u32 u0[8], u1[8], u2[8];
#pragma unroll
  for (int i = 0; i < 8; ++i) {
    u0[i] = __float_as_uint(f[i]);
    const float r1 = f[i] - __uint_as_float(u0[i] & 0xFFFF0000u);
    u1[i] = __float_as_uint(r1);
    const float r2 = r1 - __uint_as_float(u1[i] & 0xFFFF0000u);
    u2[i] = __float_as_uint(r2);
  }
  const size_t base = ((size_t)s * 2 + h) * 256 + l * 4;
#define PK(U) make_uint4((U[0]>>16)|(U[1]&0xFFFF0000u), (U[2]>>16)|(U[3]&0xFFFF0000u), \
                         (U[4]>>16)|(U[5]&0xFFFF0000u), (U[6]>>16)|(U[7]&0xFFFF0000u))
  *(uint4*)(wfrag + base)                 = PK(u0);
  *(uint4*)(wfrag + base + 128 * 512)     = PK(u1);   // plane stride = 128*2*256 words
  *(uint4*)(wfrag + base + 2 * 128 * 512) = PK(u2);
#undef PK
}

// ---------------- Kernel M: fused GEMM + in-block k-reduction + epilogue ----------------
// 512 blocks x 8 waves; block owns 16 rows, wave w owns k-slice w*512.
// x prefetched via global_load_lds (fire-and-forget: cannot be sunk by the scheduler)
// through a per-wave depth-3 LDS ring, 3 steps ahead -> 6 loads always in flight.
// Deterministic waits: B reg-loads are issued & consumed within one iteration (compiler
// waits them at the MFMAs), so at iteration top only the 6 x-prefetches are outstanding:
// vmcnt(4) retires exactly step sl. lgkmcnt(0) before ring reuse kills the overwrite race.
// Numerics bitwise-identical to prior rounds (same elements->same split->same MFMA/reduce).
__global__ __launch_bounds__(512, 4)
void gate_mega(const float* __restrict__ x, const u32* __restrict__ wfrag,
               const float* __restrict__ noise, const float* __restrict__ gw2,
               float* __restrict__ out, float* __restrict__ part2) {
  __shared__ __align__(16) float lds_x[8][3][512];   // per-wave x ring: 3 x 2KB, 48 KB
  __shared__ float red[8][512];                      // [wave][e*16 + row], 16 KB
  __shared__ float sg2[256];
  const int t = threadIdx.x;
  const int w = t >> 6, l = t & 63;
  const int rt = blockIdx.x;         // 16-row tile 0..511
  if (t < 256) sg2[t] = gw2[t];

  const int r = l & 15, c = l >> 4;
  // lane l's 8 floats per step: x[rt*16+r][w*512 + c*8 + sl*32 .. +8]
  const float* gx = x + (size_t)(rt * 16 + r) * DD + w * 512 + (c << 3);
  const u32* wfl = wfrag + (size_t)l * 4 + (size_t)(w * 16) * 512;

  f32x4 ag0 = {0,0,0,0}, ag1 = ag0, ag2 = ag0, an0 = ag0, an1 = ag0, an2 = ag0;

  // prologue: prefetch steps 0,1,2 (6 loads in flight)
  GLD(gx + 0 * 32,     &lds_x[w][0][0]);
  GLD(gx + 0 * 32 + 4, &lds_x[w][0][256]);
  GLD(gx + 1 * 32,     &lds_x[w][1][0]);
  GLD(gx + 1 * 32 + 4, &lds_x[w][1][256]);
  GLD(gx + 2 * 32,     &lds_x[w][2][0]);
  GLD(gx + 2 * 32 + 4, &lds_x[w][2][256]);

#pragma unroll
  for (int sl = 0; sl < 16; ++sl) {
    // retire exactly step sl's two loads (younger: 4 at sl<=13, 2 at 14, 0 at 15)
    if (sl <= 13)      asm volatile("s_waitcnt vmcnt(4)" ::: "memory");
    else if (sl == 14) asm volatile("s_waitcnt vmcnt(2)" ::: "memory");
    else               asm volatile("s_waitcnt vmcnt(0)" ::: "memory");

    // lane reads its own 32B slot: stride 16B -> 2-way bank aliasing (free)
    const float* xb = &lds_x[w][sl % 3][0];
    const f32x4 q0 = *(const f32x4*)(xb + (l << 2));
    const f32x4 q1 = *(const f32x4*)(xb + 256 + (l << 2));

    // B frags for this step (issued & consumed within the iteration)
    const u32* wb = wfl + (size_t)sl * 512;
    const bf16x8 bg0 = *(const bf16x8*)(wb);
    const bf16x8 bn0 = *(const bf16x8*)(wb + 256);
    const bf16x8 bg1 = *(const bf16x8*)(wb + 128 * 512);
    const bf16x8 bn1 = *(const bf16x8*)(wb + 128 * 512 + 256);
    const bf16x8 bg2 = *(const bf16x8*)(wb + 2 * 128 * 512);
    const bf16x8 bn2 = *(const bf16x8*)(wb + 2 * 128 * 512 + 256);

    // exact 3-plane split (identical ops/order to prior rounds)
    u32 pk[12] __attribute__((aligned(16)));
#pragma unroll
    for (int p = 0; p < 4; ++p) {
      const float fa = (p < 2 ? q0 : q1)[(p & 1) * 2];
      const float fb = (p < 2 ? q0 : q1)[(p & 1) * 2 + 1];
      const u32  a  = __float_as_uint(fa);
      const float ra1 = fa - __uint_as_float(a & 0xFFFF0000u);
      const u32  a1 = __float_as_uint(ra1);
      const float ra2 = ra1 - __uint_as_float(a1 & 0xFFFF0000u);
      const u32  a2 = __float_as_uint(ra2);
      const u32  b  = __float_as_uint(fb);
      const float rb1 = fb - __uint_as_float(b & 0xFFFF0000u);
      const u32  b1 = __float_as_uint(rb1);
      const float rb2 = rb1 - __uint_as_float(b1 & 0xFFFF0000u);
      const u32  b2 = __float_as_uint(rb2);
      pk[p]     = (a  >> 16) | (b  & 0xFFFF0000u);
      pk[4 + p] = (a1 >> 16) | (b1 & 0xFFFF0000u);
      pk[8 + p] = (a2 >> 16) | (b2 & 0xFFFF0000u);
    }
    const bf16x8 a0 = *(const bf16x8*)&pk[0];
    const bf16x8 a1 = *(const bf16x8*)&pk[4];
    const bf16x8 a2 = *(const bf16x8*)&pk[8];

    // ds_reads of this buffer are complete -> safe to re-target it for step sl+3
    asm volatile("s_waitcnt lgkmcnt(0)" ::: "memory");
    if (sl + 3 < 16) {
      GLD(gx + (sl + 3) * 32,     &lds_x[w][sl % 3][0]);
      GLD(gx + (sl + 3) * 32 + 4, &lds_x[w][sl % 3][256]);
    }

    ag0 = __builtin_amdgcn_mfma_f32_16x16x32_bf16(a0, bg0, ag0, 0, 0, 0);
    an0 = __builtin_amdgcn_mfma_f32_16x16x32_bf16(a0, bn0, an0, 0, 0, 0);
    ag1 = __builtin_amdgcn_mfma_f32_16x16x32_bf16(a0, bg1, ag1, 0, 0, 0);
    an1 = __builtin_amdgcn_mfma_f32_16x16x32_bf16(a0, bn1, an1, 0, 0, 0);
    ag2 = __builtin_amdgcn_mfma_f32_16x16x32_bf16(a1, bg0, ag2, 0, 0, 0);
    an2 = __builtin_amdgcn_mfma_f32_16x16x32_bf16(a1, bn0, an2, 0, 0, 0);
    ag0 = __builtin_amdgcn_mfma_f32_16x16x32_bf16(a0, bg2, ag0, 0, 0, 0);
    an0 = __builtin_amdgcn_mfma_f32_16x16x32_bf16(a0, bn2, an0, 0, 0, 0);
    ag1 = __builtin_amdgcn_mfma_f32_16x16x32_bf16(a1, bg1, ag1, 0, 0, 0);
    an1 = __builtin_amdgcn_mfma_f32_16x16x32_bf16(a1, bn1, an1, 0, 0, 0);
    ag2 = __builtin_amdgcn_mfma_f32_16x16x32_bf16(a2, bg0, ag2, 0, 0, 0);
    an2 = __builtin_amdgcn_mfma_f32_16x16x32_bf16(a2, bn0, an2, 0, 0, 0);
  }

  const f32x4 cg = ag0 + ag1 + ag2;
  const f32x4 cn = an0 + an1 + an2;
  // C/D: col(lane&15)=expert, row=(lane>>4)*4+reg [m89]. Store as [e*16+row].
#pragma unroll
  for (int j = 0; j < 4; ++j) {
    red[w][r * 16 + (c * 4 + j)]        = cg[j];
    red[w][(16 + r) * 16 + (c * 4 + j)] = cn[j];
  }
  __syncthreads();
  // 512-thread reduce across the 8 k-slices, ascending order (bitwise-stable).
  {
    float s = red[0][t];
#pragma unroll
    for (int ww = 1; ww < 8; ++ww) s += red[ww][t];
    red[0][t] = s;   // column-exclusive per thread: no race
  }
  __syncthreads();

  if (t < 16) {
    const int row = rt * 16 + t;
    float dot[32];
#pragma unroll
    for (int e = 0; e < 32; ++e) dot[e] = red[0][e * 16 + t];
    float h[16];
#pragma unroll
    for (int e = 0; e < 16; ++e) h[e] = tanhf(dot[e]);
    float lg[16], nc[16], ln[16], lo[16];
#pragma unroll
    for (int j = 0; j < 16; ++j) {
      float s = 0.f;
#pragma unroll
      for (int e = 0; e < 16; ++e) s = fmaf(h[e], sg2[j * 16 + e], s);
      lg[j] = s;
      const float v = dot[16 + j];
      nc[j] = fmaxf(v, 0.f) + log1pf(expf(-fabsf(v))) + 0.01f;
      ln[j] = noise[(size_t)row * 16 + j] * nc[j];
      lo[j] = lg[j] + ln[j];
    }
    int i0 = 0; float m0 = lo[0];
#pragma unroll
    for (int j = 1; j < 16; ++j) if (lo[j] > m0) { m0 = lo[j]; i0 = j; }
    int i1 = -1; float m1 = -1e30f;
#pragma unroll
    for (int j = 0; j < 16; ++j) if (j != i0 && lo[j] > m1) { m1 = lo[j]; i1 = j; }
    float m2 = -1e30f;
#pragma unroll
    for (int j = 0; j < 16; ++j) if (j != i0 && j != i1 && lo[j] > m2) m2 = lo[j];

    const float e1 = expf(m1 - m0);
    const float s0 = 1.f / (1.f + e1);
    const float s1 = e1 / (1.f + e1);
    out[(size_t)row * 2]             = (float)i0;
    out[(size_t)row * 2 + 1]         = (float)i1;
    out[16384 + (size_t)row * 2]     = s0;
    out[16384 + (size_t)row * 2 + 1] = s1;

    float cacc[32];
#pragma unroll
    for (int j = 0; j < 16; ++j) {
      cacc[j] = (j == i0) ? s0 : ((j == i1) ? s1 : 0.f);
      const bool in = ln[j] > m2;
      const float thr = in ? m2 : m1;
      const float z = (lg[j] - thr) / nc[j];
      cacc[16 + j] = 0.5f * (1.f + erff(z * 0.70710678118654752f));
    }
    // reduce the 32 loss partials across the 16 row-lanes
#pragma unroll
    for (int off = 1; off < 16; off <<= 1) {
#pragma unroll
      for (int k = 0; k < 32; ++k) cacc[k] += __shfl_xor(cacc[k], off, 16);
    }
    // lane t writes partial for expert t (static selection to avoid scratch)
    float v0 = 0.f, v1 = 0.f;
#pragma unroll
    for (int k = 0; k < 16; ++k) if (t == k) { v0 = cacc[k]; v1 = cacc[16 + k]; }
    part2[(size_t)rt * 32 + t]      = v0;
    part2[(size_t)rt * 32 + 16 + t] = v1;
  }
}

// ---------------- Kernel C: reduce per-block partials -> cv^2 loss ----------------
__global__ __launch_bounds__(256)
void gate_loss_k(const float* __restrict__ part2, float* __restrict__ out) {
  __shared__ float sred[8][32];
  const int t = threadIdx.x;        // 256
  const int k = t & 31, s = t >> 5; // expert, block-slice (8 slices of 64 blocks)
  float acc = 0.f;
#pragma unroll 8
  for (int i = 0; i < 64; ++i) acc += part2[(size_t)(s * 64 + i) * 32 + k];
  sred[s][k] = acc;
  __syncthreads();
  if (t == 0) {
    float res = 0.f;
    for (int g = 0; g < 2; ++g) {
      float vals[16];
      float mu = 0.f;
      for (int j = 0; j < 16; ++j) {
        float s2 = 0.f;
        for (int ss = 0; ss < 8; ++ss) s2 += sred[ss][g * 16 + j];
        vals[j] = s2;
        mu += s2;
      }
      mu *= (1.f / 16.f);
      float var = 0.f;
      for (int j = 0; j < 16; ++j) { const float d = vals[j] - mu; var += d * d; }
      var *= (1.f / 15.f);
      res += var / (mu * mu + 1e-10f);
    }
    out[32768] = res * 0.01f;
  }
}

extern "C" void kernel_launch(void* const* d_in, const int* in_sizes, int n_in,
                              void* d_out, int out_size, void* d_ws, size_t ws_size,
                              hipStream_t stream) {
  const float* x     = (const float*)d_in[0];
  const float* gw1   = (const float*)d_in[1];
  const float* gw2   = (const float*)d_in[2];
  const float* nw    = (const float*)d_in[3];
  const float* noise = (const float*)d_in[4];
  float* out   = (float*)d_out;
  u32*   wfrag = (u32*)d_ws;                                   // 768 KB, fully written
  float* part2 = (float*)((char*)d_ws + (size_t)768 * 1024);   // 64 KB, fully written
  split_w<<<128, 128, 0, stream>>>(gw1, nw, wfrag);
  gate_mega<<<512, 512, 0, stream>>>(x, wfrag, noise, gw2, out, part2);
  gate_loss_k<<<1, 256, 0, stream>>>(part2, out);
}

// Round 6
// 61.208 us; speedup vs baseline: 1.2236x; 1.0304x over previous
//
#include <hip/hip_runtime.h>
#include <math.h>

#define TT 8192
#define DD 4096

typedef float  f32x4  __attribute__((ext_vector_type(4)));
typedef short  bf16x8 __attribute__((ext_vector_type(8)));
typedef unsigned int u32;

typedef __attribute__((address_space(3))) void        lds_vp;
typedef const __attribute__((address_space(1))) void  gbl_vp;
// async global->LDS: lane l's 16B lands at lptr + l*16 (wave-uniform lptr, per-lane src)
#define GLD(gp_, lp_) __builtin_amdgcn_global_load_lds((gbl_vp*)(gp_), (lds_vp*)(lp_), 16, 0, 0)

// ---------------- Kernel P: split weights into 3 bf16 planes, frag-ordered ----------------
// wfrag word layout: ((p*128 + S)*2 + h)*256 + l*4  (uint4 per lane = 8 bf16)
// k = S*32 + (l>>4)*8 + i ; expert e = h*16 + (l&15).
__global__ __launch_bounds__(128)
void split_w(const float* __restrict__ gw1, const float* __restrict__ nw,
             u32* __restrict__ wfrag) {
  const int s = blockIdx.x;          // 128 k-steps
  const int t = threadIdx.x;
  const int h = t >> 6, l = t & 63;
  const int e = h * 16 + (l & 15);
  const float* src = ((e < 16) ? (gw1 + (size_t)e * DD) : (nw + (size_t)(e - 16) * DD))
                     + s * 32 + ((l >> 4) << 3);
  float f[8];
  *(float4*)&f[0] = *(const float4*)src;
  *(float4*)&f[4] = *(const float4*)(src + 4);
  u32 u0[8], u1[8], u2[8];
#pragma unroll
  for (int i = 0; i < 8; ++i) {
    u0[i] = __float_as_uint(f[i]);
    const float r1 = f[i] - __uint_as_float(u0[i] & 0xFFFF0000u);
    u1[i] = __float_as_uint(r1);
    const float r2 = r1 - __uint_as_float(u1[i] & 0xFFFF0000u);
    u2[i] = __float_as_uint(r2);
  }
  const size_t base = ((size_t)s * 2 + h) * 256 + l * 4;
#define PK(U) make_uint4((U[0]>>16)|(U[1]&0xFFFF0000u), (U[2]>>16)|(U[3]&0xFFFF0000u), \
                         (U[4]>>16)|(U[5]&0xFFFF0000u), (U[6]>>16)|(U[7]&0xFFFF0000u))
  *(uint4*)(wfrag + base)                 = PK(u0);
  *(uint4*)(wfrag + base + 128 * 512)     = PK(u1);   // plane stride = 128*2*256 words
  *(uint4*)(wfrag + base + 2 * 128 * 512) = PK(u2);
#undef PK
}

// ---------------- Kernel M: fused GEMM, B shared block-wide via LDS double buffer ----------
// 256 blocks x 16 waves (1024 thr). Wave v: k-slice w=v&7, row-tile m=v>>3 (block = 32 rows).
// B staged once per block per k-step (48 x 1KB chunks, 3 per wave) via global_load_lds into
// a 2-deep LDS ring: halves per-CU B line traffic AND pipelines the fill one iteration deep
// (issue at iter start, vmcnt(0)+s_barrier at iter end = full-iteration latency cover).
// Numerics bitwise-identical to prior rounds (same elements -> same split -> same MFMA order
// -> same ascending-slice reduce; part2 grouping unchanged).
__global__ __launch_bounds__(1024, 4)
void gate_mega(const float* __restrict__ x, const u32* __restrict__ wfrag,
               const float* __restrict__ noise, const float* __restrict__ gw2,
               float* __restrict__ out, float* __restrict__ part2) {
  __shared__ __align__(16) u32 ldsb[2][8][6][256];   // 96 KB: B double buffer
  __shared__ float red[8][1024];                      // 32 KB: [slice][m*512 + e*16 + row]
  __shared__ float sg2[256];
  const int t = threadIdx.x;
  const int v = t >> 6, l = t & 63;
  const int w = v & 7;                 // k-slice (512 k)
  const int m = v >> 3;                // row-tile half (16 rows)
  const int rt = blockIdx.x;           // 32-row tile 0..255
  if (t < 256) sg2[t] = gw2[t];

  const int r = l & 15, c = l >> 4;
  const float* xp = x + (size_t)(rt * 32 + m * 16 + r) * DD + w * 512 + (c << 3);

  // wave v stages chunks q=3v..3v+2: slice s=q/6, part p=q%6 (plane p>>1, half p&1)
  // src word = (p>>1)*65536 + (p&1)*256 + (s*16+sl)*512 + l*4
  const u32* srcb[3];
  u32* dst0[3];
  u32* dst1[3];
#pragma unroll
  for (int i = 0; i < 3; ++i) {
    const int q = 3 * v + i, s = q / 6, p = q % 6;
    srcb[i] = wfrag + (size_t)(p >> 1) * 65536 + (p & 1) * 256
                    + (size_t)s * 16 * 512 + (l << 2);
    dst0[i] = &ldsb[0][s][p][0];
    dst1[i] = &ldsb[1][s][p][0];
  }

  // prologue: stage step 0 into buf0
#pragma unroll
  for (int i = 0; i < 3; ++i) GLD(srcb[i], dst0[i]);
  asm volatile("s_waitcnt vmcnt(0)" ::: "memory");
  asm volatile("s_barrier" ::: "memory");

  f32x4 ag0 = {0,0,0,0}, ag1 = ag0, ag2 = ag0, an0 = ag0, an1 = ag0, an2 = ag0;

#pragma unroll 2
  for (int sl = 0; sl < 16; ++sl) {
    // stage step sl+1 into the other buffer (fire-and-forget; full iter of cover)
    if (sl + 1 < 16) {
#pragma unroll
      for (int i = 0; i < 3; ++i)
        GLD(srcb[i] + (size_t)(sl + 1) * 512, (sl & 1) ? dst0[i] : dst1[i]);
    }

    // consume buf[sl&1]: B frags (validated by prev iter's vmcnt(0)+barrier)
    const u32* wb = &ldsb[sl & 1][w][0][0] + (l << 2);
    const bf16x8 bg0 = *(const bf16x8*)(wb);
    const bf16x8 bn0 = *(const bf16x8*)(wb + 256);
    const bf16x8 bg1 = *(const bf16x8*)(wb + 512);
    const bf16x8 bn1 = *(const bf16x8*)(wb + 768);
    const bf16x8 bg2 = *(const bf16x8*)(wb + 1024);
    const bf16x8 bn2 = *(const bf16x8*)(wb + 1280);

    float f[8];
    *(float4*)&f[0] = *(const float4*)(xp + sl * 32);
    *(float4*)&f[4] = *(const float4*)(xp + sl * 32 + 4);

    // exact 3-plane split (identical ops/order to prior rounds)
    u32 pk[12] __attribute__((aligned(16)));
#pragma unroll
    for (int p = 0; p < 4; ++p) {
      const float fa = f[2 * p], fb = f[2 * p + 1];
      const u32  a  = __float_as_uint(fa);
      const float ra1 = fa - __uint_as_float(a & 0xFFFF0000u);
      const u32  a1 = __float_as_uint(ra1);
      const float ra2 = ra1 - __uint_as_float(a1 & 0xFFFF0000u);
      const u32  a2 = __float_as_uint(ra2);
      const u32  b  = __float_as_uint(fb);
      const float rb1 = fb - __uint_as_float(b & 0xFFFF0000u);
      const u32  b1 = __float_as_uint(rb1);
      const float rb2 = rb1 - __uint_as_float(b1 & 0xFFFF0000u);
      const u32  b2 = __float_as_uint(rb2);
      pk[p]     = (a  >> 16) | (b  & 0xFFFF0000u);
      pk[4 + p] = (a1 >> 16) | (b1 & 0xFFFF0000u);
      pk[8 + p] = (a2 >> 16) | (b2 & 0xFFFF0000u);
    }
    const bf16x8 a0 = *(const bf16x8*)&pk[0];
    const bf16x8 a1 = *(const bf16x8*)&pk[4];
    const bf16x8 a2 = *(const bf16x8*)&pk[8];

    ag0 = __builtin_amdgcn_mfma_f32_16x16x32_bf16(a0, bg0, ag0, 0, 0, 0);
    an0 = __builtin_amdgcn_mfma_f32_16x16x32_bf16(a0, bn0, an0, 0, 0, 0);
    ag1 = __builtin_amdgcn_mfma_f32_16x16x32_bf16(a0, bg1, ag1, 0, 0, 0);
    an1 = __builtin_amdgcn_mfma_f32_16x16x32_bf16(a0, bn1, an1, 0, 0, 0);
    ag2 = __builtin_amdgcn_mfma_f32_16x16x32_bf16(a1, bg0, ag2, 0, 0, 0);
    an2 = __builtin_amdgcn_mfma_f32_16x16x32_bf16(a1, bn0, an2, 0, 0, 0);
    ag0 = __builtin_amdgcn_mfma_f32_16x16x32_bf16(a0, bg2, ag0, 0, 0, 0);
    an0 = __builtin_amdgcn_mfma_f32_16x16x32_bf16(a0, bn2, an0, 0, 0, 0);
    ag1 = __builtin_amdgcn_mfma_f32_16x16x32_bf16(a1, bg1, ag1, 0, 0, 0);
    an1 = __builtin_amdgcn_mfma_f32_16x16x32_bf16(a1, bn1, an1, 0, 0, 0);
    ag2 = __builtin_amdgcn_mfma_f32_16x16x32_bf16(a2, bg0, ag2, 0, 0, 0);
    an2 = __builtin_amdgcn_mfma_f32_16x16x32_bf16(a2, bn0, an2, 0, 0, 0);

    // publish: my next-step GLDs done + everyone finished reading buf[sl&1]
    asm volatile("s_waitcnt vmcnt(0)" ::: "memory");
    asm volatile("s_barrier" ::: "memory");
  }

  const f32x4 cg = ag0 + ag1 + ag2;
  const f32x4 cn = an0 + an1 + an2;
  // C/D: col(lane&15)=expert, row=(lane>>4)*4+reg [m89]. Store as [m*512 + e*16 + row].
#pragma unroll
  for (int j = 0; j < 4; ++j) {
    red[w][m * 512 + r * 16 + (c * 4 + j)]        = cg[j];
    red[w][m * 512 + (16 + r) * 16 + (c * 4 + j)] = cn[j];
  }
  __syncthreads();
  // 1024-thread reduce across the 8 k-slices, ascending order (bitwise-stable).
  {
    float s = red[0][t];
#pragma unroll
    for (int ww = 1; ww < 8; ++ww) s += red[ww][t];
    red[0][t] = s;   // column-exclusive per thread: no race
  }
  __syncthreads();

  if (t < 32) {
    const int mg = t >> 4, rr = t & 15;
    const int row = rt * 32 + t;
    float dot[32];
#pragma unroll
    for (int e = 0; e < 32; ++e) dot[e] = red[0][mg * 512 + e * 16 + rr];
    float h[16];
#pragma unroll
    for (int e = 0; e < 16; ++e) h[e] = tanhf(dot[e]);
    float lg[16], nc[16], ln[16], lo[16];
#pragma unroll
    for (int j = 0; j < 16; ++j) {
      float s = 0.f;
#pragma unroll
      for (int e = 0; e < 16; ++e) s = fmaf(h[e], sg2[j * 16 + e], s);
      lg[j] = s;
      const float vv = dot[16 + j];
      nc[j] = fmaxf(vv, 0.f) + log1pf(expf(-fabsf(vv))) + 0.01f;
      ln[j] = noise[(size_t)row * 16 + j] * nc[j];
      lo[j] = lg[j] + ln[j];
    }
    int i0 = 0; float m0 = lo[0];
#pragma unroll
    for (int j = 1; j < 16; ++j) if (lo[j] > m0) { m0 = lo[j]; i0 = j; }
    int i1 = -1; float m1 = -1e30f;
#pragma unroll
    for (int j = 0; j < 16; ++j) if (j != i0 && lo[j] > m1) { m1 = lo[j]; i1 = j; }
    float m2 = -1e30f;
#pragma unroll
    for (int j = 0; j < 16; ++j) if (j != i0 && j != i1 && lo[j] > m2) m2 = lo[j];

    const float e1 = expf(m1 - m0);
    const float s0 = 1.f / (1.f + e1);
    const float s1 = e1 / (1.f + e1);
    out[(size_t)row * 2]             = (float)i0;
    out[(size_t)row * 2 + 1]         = (float)i1;
    out[16384 + (size_t)row * 2]     = s0;
    out[16384 + (size_t)row * 2 + 1] = s1;

    float cacc[32];
#pragma unroll
    for (int j = 0; j < 16; ++j) {
      cacc[j] = (j == i0) ? s0 : ((j == i1) ? s1 : 0.f);
      const bool in = ln[j] > m2;
      const float thr = in ? m2 : m1;
      const float z = (lg[j] - thr) / nc[j];
      cacc[16 + j] = 0.5f * (1.f + erff(z * 0.70710678118654752f));
    }
    // reduce the 32 loss partials across each 16-row group (xor<16 stays in-group)
#pragma unroll
    for (int off = 1; off < 16; off <<= 1) {
#pragma unroll
      for (int k = 0; k < 32; ++k) cacc[k] += __shfl_xor(cacc[k], off, 16);
    }
    // group g = rt*2 + mg keeps the exact part2 layout/order of prior rounds
    const int g = rt * 2 + mg;
    float v0 = 0.f, v1 = 0.f;
#pragma unroll
    for (int k = 0; k < 16; ++k) if (rr == k) { v0 = cacc[k]; v1 = cacc[16 + k]; }
    part2[(size_t)g * 32 + rr]      = v0;
    part2[(size_t)g * 32 + 16 + rr] = v1;
  }
}

// ---------------- Kernel C: reduce per-block partials -> cv^2 loss ----------------
__global__ __launch_bounds__(256)
void gate_loss_k(const float* __restrict__ part2, float* __restrict__ out) {
  __shared__ float sred[8][32];
  const int t = threadIdx.x;        // 256
  const int k = t & 31, s = t >> 5; // expert, block-slice (8 slices of 64 groups)
  float acc = 0.f;
#pragma unroll 8
  for (int i = 0; i < 64; ++i) acc += part2[(size_t)(s * 64 + i) * 32 + k];
  sred[s][k] = acc;
  __syncthreads();
  if (t == 0) {
    float res = 0.f;
    for (int g = 0; g < 2; ++g) {
      float vals[16];
      float mu = 0.f;
      for (int j = 0; j < 16; ++j) {
        float s2 = 0.f;
        for (int ss = 0; ss < 8; ++ss) s2 += sred[ss][g * 16 + j];
        vals[j] = s2;
        mu += s2;
      }
      mu *= (1.f / 16.f);
      float var = 0.f;
      for (int j = 0; j < 16; ++j) { const float d = vals[j] - mu; var += d * d; }
      var *= (1.f / 15.f);
      res += var / (mu * mu + 1e-10f);
    }
    out[32768] = res * 0.01f;
  }
}

extern "C" void kernel_launch(void* const* d_in, const int* in_sizes, int n_in,
                              void* d_out, int out_size, void* d_ws, size_t ws_size,
                              hipStream_t stream) {
  const float* x     = (const float*)d_in[0];
  const float* gw1   = (const float*)d_in[1];
  const float* gw2   = (const float*)d_in[2];
  const float* nw    = (const float*)d_in[3];
  const float* noise = (const float*)d_in[4];
  float* out   = (float*)d_out;
  u32*   wfrag = (u32*)d_ws;                                   // 768 KB, fully written
  float* part2 = (float*)((char*)d_ws + (size_t)768 * 1024);   // 64 KB, fully written
  split_w<<<128, 128, 0, stream>>>(gw1, nw, wfrag);
  gate_mega<<<256, 1024, 0, stream>>>(x, wfrag, noise, gw2, out, part2);
  gate_loss_k<<<1, 256, 0, stream>>>(part2, out);
}